// Round 1
// baseline (5703.703 us; speedup 1.0000x reference)
//
#include <hip/hip_runtime.h>
#include <stdint.h>

// Problem constants
#define NB   32
#define TSEQ 4096
#define DD   256
#define PP   2
#define KK   17
#define LL   3
#define NHH  8
#define HDD  32
#define FFD  2048
#define HIDD 128
#define ROWS 1088                    // B*P*K
#define SCALE 0.17677669529663689f   // 1/sqrt(32)

// ---------- bf16 helpers (raw ushort, OCP bf16 = fp32 truncated w/ RNE) ----------
static __device__ __forceinline__ float bflo(unsigned int u) {
  union { unsigned int i; float f; } v; v.i = u << 16; return v.f;
}
static __device__ __forceinline__ float bfhi(unsigned int u) {
  union { unsigned int i; float f; } v; v.i = u & 0xffff0000u; return v.f;
}
static __device__ __forceinline__ unsigned short f2bf(float f) {
  unsigned int x = __float_as_uint(f);
  return (unsigned short)((x + 0x7fffu + ((x >> 16) & 1u)) >> 16);
}

// ---------- x init: x[b,p,k,:] = person_q[p] + key_q[k] ----------
__global__ __launch_bounds__(256) void init_x_kernel(
    const float* __restrict__ person_q, const float* __restrict__ key_q,
    float* __restrict__ x) {
  const int row = blockIdx.x, tid = threadIdx.x;
  const int p = (row / KK) & 1, k = row % KK;
  x[(size_t)row * DD + tid] = person_q[p * DD + tid] + key_q[k * DD + tid];
}

// ---------- generic fp32 GEMM: Y = act(X @ W^T + bias) [+ R] ----------
// X (M,K) row-major, W rows of length >= K with stride wstride, Y (M,N).
// M must be a multiple of 64. K a multiple of 16. N guarded.
__global__ __launch_bounds__(256) void gemm_kernel(
    const float* __restrict__ X, const float* __restrict__ W,
    const float* __restrict__ bias, const float* __restrict__ R,
    float* __restrict__ Y, int M, int N, int K, int wstride, int relu) {
  __shared__ float As[16][68];   // [kk][m]
  __shared__ float Bs[16][68];   // [kk][n]
  const int tid = threadIdx.x;
  const int m0 = blockIdx.y * 64, n0 = blockIdx.x * 64;
  const int tr = tid >> 4, tc = tid & 15;
  const int lr = tid >> 2, lk = (tid & 3) << 2;
  float acc[4][4] = {{0.f, 0.f, 0.f, 0.f}, {0.f, 0.f, 0.f, 0.f},
                     {0.f, 0.f, 0.f, 0.f}, {0.f, 0.f, 0.f, 0.f}};
  for (int k0 = 0; k0 < K; k0 += 16) {
    const float4 av = *reinterpret_cast<const float4*>(&X[(size_t)(m0 + lr) * K + k0 + lk]);
    int wn = n0 + lr; if (wn >= N) wn = N - 1;
    const float4 bv = *reinterpret_cast<const float4*>(&W[(size_t)wn * wstride + k0 + lk]);
    __syncthreads();
    As[lk + 0][lr] = av.x; As[lk + 1][lr] = av.y; As[lk + 2][lr] = av.z; As[lk + 3][lr] = av.w;
    Bs[lk + 0][lr] = bv.x; Bs[lk + 1][lr] = bv.y; Bs[lk + 2][lr] = bv.z; Bs[lk + 3][lr] = bv.w;
    __syncthreads();
#pragma unroll
    for (int kk = 0; kk < 16; ++kk) {
      const float4 a = *reinterpret_cast<const float4*>(&As[kk][tr << 2]);
      const float4 b = *reinterpret_cast<const float4*>(&Bs[kk][tc << 2]);
      const float aa[4] = {a.x, a.y, a.z, a.w};
      const float bb[4] = {b.x, b.y, b.z, b.w};
#pragma unroll
      for (int r = 0; r < 4; ++r)
#pragma unroll
        for (int c = 0; c < 4; ++c) acc[r][c] += aa[r] * bb[c];
    }
  }
#pragma unroll
  for (int r = 0; r < 4; ++r) {
    const int m = m0 + (tr << 2) + r;
#pragma unroll
    for (int c = 0; c < 4; ++c) {
      const int n = n0 + (tc << 2) + c;
      if (n < N) {
        float o = acc[r][c];
        if (bias) o += bias[n];
        if (relu) o = fmaxf(o, 0.f);
        if (R) o += R[(size_t)m * N + n];
        Y[(size_t)m * N + n] = o;
      }
    }
  }
}

// ---------- self-attention over K=17 keypoints, one block per (b,p,h) ----------
__global__ __launch_bounds__(64) void sa_attn_kernel(
    const float* __restrict__ qkv, float* __restrict__ attn_o) {
  const int blk = blockIdx.x;         // 512 = 64 bp * 8 h
  const int h = blk & 7, bp = blk >> 3;
  const int rowbase = bp * KK;
  const int tid = threadIdx.x;
  __shared__ float qs[KK][36], ks[KK][36], vs[KK][36];
  __shared__ float ss[KK][20];
  __shared__ float lsum[KK];
  for (int i = tid; i < KK * HDD; i += 64) {
    const int r = i >> 5, d = i & 31;
    const size_t base = (size_t)(rowbase + r) * 768 + h * 32 + d;
    qs[r][d] = qkv[base];
    ks[r][d] = qkv[base + 256];
    vs[r][d] = qkv[base + 512];
  }
  __syncthreads();
  for (int i = tid; i < KK * KK; i += 64) {
    const int q = i / KK, k = i % KK;
    float s = 0.f;
#pragma unroll
    for (int d = 0; d < HDD; ++d) s += qs[q][d] * ks[k][d];
    ss[q][k] = s * SCALE;
  }
  __syncthreads();
  if (tid < KK) {
    float m = -1e30f;
    for (int k = 0; k < KK; ++k) m = fmaxf(m, ss[tid][k]);
    float l = 0.f;
    for (int k = 0; k < KK; ++k) { const float e = __expf(ss[tid][k] - m); ss[tid][k] = e; l += e; }
    lsum[tid] = l;
  }
  __syncthreads();
  for (int i = tid; i < KK * HDD; i += 64) {
    const int q = i >> 5, d = i & 31;
    float o = 0.f;
#pragma unroll
    for (int k = 0; k < KK; ++k) o += ss[q][k] * vs[k][d];
    attn_o[(size_t)(rowbase + q) * DD + h * 32 + d] = o / lsum[q];
  }
}

// ---------- qk_eff[r,h,c] = scale * sum_j q[r, h*32+j] * Wk[h*32+j, c] ----------
__global__ __launch_bounds__(256) void qkeff_kernel(
    const float* __restrict__ q_ca, const float* __restrict__ ca_in_w_l,
    float* __restrict__ qk_eff) {
  const int r = blockIdx.x, tid = threadIdx.x;
  __shared__ float qrow[DD];
  qrow[tid] = q_ca[(size_t)r * DD + tid];
  __syncthreads();
#pragma unroll
  for (int h = 0; h < NHH; ++h) {
    float acc = 0.f;
#pragma unroll
    for (int j = 0; j < 32; ++j)
      acc += qrow[h * 32 + j] * ca_in_w_l[(size_t)(DD + h * 32 + j) * DD + tid];
    qk_eff[(size_t)r * 2048 + h * 256 + tid] = acc * SCALE;
  }
}

// ---------- fused cross-attention (flash, online softmax over T=4096) ----------
// one block per (b,p,h); ctx[r, h*256+c] = softmax(qk_eff . mem_t) . memory
#define TT 32
__global__ __launch_bounds__(256) void ca_flash_kernel(
    const float* __restrict__ qk_eff, const float* __restrict__ memory,
    float* __restrict__ ctx) {
  const int blk = blockIdx.x;         // 512
  const int h = blk & 7, bp = blk >> 3;
  const int b = bp >> 1;
  const int rowbase = bp * KK;
  const int tid = threadIdx.x;

  __shared__ float qks[KK][260];
  __shared__ unsigned short mems[TT][264];
  __shared__ float plds[KK][36];
  __shared__ float mrow[KK], lrow[KK], rrow[KK];

  for (int i = tid; i < KK * DD; i += 256) {
    const int q = i >> 8, c = i & 255;
    qks[q][c] = qk_eff[(size_t)(rowbase + q) * 2048 + h * 256 + c];
  }
  if (tid < KK) { mrow[tid] = -1e30f; lrow[tid] = 0.f; }
  float cacc[KK];
#pragma unroll
  for (int q = 0; q < KK; ++q) cacc[q] = 0.f;

  const float* memb = memory + (size_t)b * TSEQ * DD;

  for (int t0 = 0; t0 < TSEQ; t0 += TT) {
    __syncthreads();  // protect mems/plds from previous-iteration readers
    // stage TT x 256 as bf16
    for (int cid = tid; cid < TT * 32; cid += 256) {
      const int t = cid >> 5, c8 = (cid & 31) << 3;
      const float* src = memb + (size_t)(t0 + t) * DD + c8;
      const float4 f0 = *reinterpret_cast<const float4*>(src);
      const float4 f1 = *reinterpret_cast<const float4*>(src + 4);
      uint4 st;
      st.x = (unsigned)f2bf(f0.x) | ((unsigned)f2bf(f0.y) << 16);
      st.y = (unsigned)f2bf(f0.z) | ((unsigned)f2bf(f0.w) << 16);
      st.z = (unsigned)f2bf(f1.x) | ((unsigned)f2bf(f1.y) << 16);
      st.w = (unsigned)f2bf(f1.z) | ((unsigned)f2bf(f1.w) << 16);
      *reinterpret_cast<uint4*>(&mems[t][c8]) = st;
    }
    __syncthreads();
    // scores
    for (int i = tid; i < KK * TT; i += 256) {
      const int q = i >> 5, t = i & (TT - 1);
      float s = 0.f;
#pragma unroll 4
      for (int c = 0; c < DD; c += 8) {
        const float4 qa = *reinterpret_cast<const float4*>(&qks[q][c]);
        const float4 qb = *reinterpret_cast<const float4*>(&qks[q][c + 4]);
        const uint4 mv = *reinterpret_cast<const uint4*>(&mems[t][c]);
        s += qa.x * bflo(mv.x) + qa.y * bfhi(mv.x)
           + qa.z * bflo(mv.y) + qa.w * bfhi(mv.y)
           + qb.x * bflo(mv.z) + qb.y * bfhi(mv.z)
           + qb.z * bflo(mv.w) + qb.w * bfhi(mv.w);
      }
      plds[q][t] = s;
    }
    __syncthreads();
    if (tid < KK) {
      float mt = -1e30f;
      for (int t = 0; t < TT; ++t) mt = fmaxf(mt, plds[tid][t]);
      const float mn = fmaxf(mrow[tid], mt);
      rrow[tid] = __expf(mrow[tid] - mn);
      mrow[tid] = mn;
    }
    __syncthreads();
    for (int i = tid; i < KK * TT; i += 256) {
      const int q = i >> 5, t = i & (TT - 1);
      plds[q][t] = __expf(plds[q][t] - mrow[q]);
    }
    __syncthreads();
    if (tid < KK) {
      float ssum = 0.f;
      for (int t = 0; t < TT; ++t) ssum += plds[tid][t];
      lrow[tid] = lrow[tid] * rrow[tid] + ssum;
    }
    // ctx update: this thread owns column d = tid
#pragma unroll
    for (int q = 0; q < KK; ++q) cacc[q] *= rrow[q];
#pragma unroll
    for (int tg = 0; tg < TT; tg += 4) {
      const float m0 = bflo(mems[tg + 0][tid]);
      const float m1 = bflo(mems[tg + 1][tid]);
      const float m2 = bflo(mems[tg + 2][tid]);
      const float m3 = bflo(mems[tg + 3][tid]);
#pragma unroll
      for (int q = 0; q < KK; ++q) {
        const float4 pv = *reinterpret_cast<const float4*>(&plds[q][tg]);
        cacc[q] += pv.x * m0 + pv.y * m1 + pv.z * m2 + pv.w * m3;
      }
    }
  }
  __syncthreads();
#pragma unroll
  for (int q = 0; q < KK; ++q)
    ctx[(size_t)(rowbase + q) * 2048 + h * 256 + tid] = cacc[q] / lrow[q];
}

// ---------- residual + LayerNorm (in-place on x) ----------
__global__ __launch_bounds__(256) void ln_kernel(
    const float* __restrict__ xin, const float* __restrict__ dlt,
    const float* __restrict__ w, const float* __restrict__ b,
    float* __restrict__ xout) {
  const int row = blockIdx.x, tid = threadIdx.x;
  const size_t base = (size_t)row * DD;
  const float v = xin[base + tid] + dlt[base + tid];
  float s = v, s2 = v * v;
#pragma unroll
  for (int off = 32; off > 0; off >>= 1) {
    s += __shfl_down(s, off);
    s2 += __shfl_down(s2, off);
  }
  __shared__ float ps[4], ps2[4];
  if ((tid & 63) == 0) { ps[tid >> 6] = s; ps2[tid >> 6] = s2; }
  __syncthreads();
  const float st = ps[0] + ps[1] + ps[2] + ps[3];
  const float st2 = ps2[0] + ps2[1] + ps2[2] + ps2[3];
  const float mean = st * (1.f / 256.f);
  const float var = st2 * (1.f / 256.f) - mean * mean;
  const float inv = rsqrtf(var + 1e-5f);
  xout[base + tid] = (v - mean) * inv * w[tid] + b[tid];
}

// ---------- W_vo[l][d'][h*256+c] = sum_j Wout[d',h*32+j] * Wv[h*32+j,c] ----------
__global__ __launch_bounds__(256) void wvo_kernel(
    const float* __restrict__ ca_in_w, const float* __restrict__ ca_out_w,
    float* __restrict__ Wvo) {
  const int bx = blockIdx.x;               // 3*256*8
  const int h = bx & 7, dp = (bx >> 3) & 255, l = bx >> 11;
  const int c = threadIdx.x;
  const float* wout = ca_out_w + (size_t)l * 65536 + (size_t)dp * 256 + h * 32;
  const float* wv = ca_in_w + (size_t)l * 196608 + (size_t)(512 + h * 32) * 256 + c;
  float acc = 0.f;
#pragma unroll
  for (int j = 0; j < 32; ++j) acc += wout[j] * wv[(size_t)j * 256];
  Wvo[((size_t)l * 256 + dp) * 2048 + h * 256 + c] = acc;
}

// ---------- bvo[l][d'] = Wout[d',:] . bv + ca_out_b[d'] ----------
__global__ __launch_bounds__(256) void bvo_kernel(
    const float* __restrict__ ca_out_w, const float* __restrict__ ca_in_b,
    const float* __restrict__ ca_out_b, float* __restrict__ bvo) {
  const int l = blockIdx.x, dp = threadIdx.x;
  float acc = ca_out_b[l * 256 + dp];
  for (int j = 0; j < 256; ++j)
    acc += ca_out_w[(size_t)l * 65536 + (size_t)dp * 256 + j] * ca_in_b[l * 768 + 512 + j];
  bvo[l * 256 + dp] = acc;
}

// ---------- refine pair-mean: hbar[i,f] = mean_j relu(u[i,f]+v[j,f]) ----------
__global__ __launch_bounds__(256) void pairmean_kernel(
    const float* __restrict__ u, const float* __restrict__ v,
    float* __restrict__ hbar) {
  const int bp = blockIdx.x, tid = threadIdx.x;
  const int r0 = bp * KK;
  __shared__ float us[KK][132], vs[KK][132];
  for (int i = tid; i < KK * HIDD; i += 256) {
    const int r = i >> 7, f = i & 127;
    us[r][f] = u[(size_t)(r0 + r) * HIDD + f];
    vs[r][f] = v[(size_t)(r0 + r) * HIDD + f];
  }
  __syncthreads();
  for (int i = tid; i < KK * HIDD; i += 256) {
    const int r = i >> 7, f = i & 127;
    float s = 0.f;
#pragma unroll
    for (int j = 0; j < KK; ++j) s += fmaxf(us[r][f] + vs[j][f], 0.f);
    hbar[(size_t)(r0 + r) * HIDD + f] = s * (1.0f / 17.0f);
  }
}

// ---------- host-side helpers ----------
static void gemm(const float* X, const float* W, const float* bias, const float* R,
                 float* Y, int M, int N, int K, int wstride, int relu, hipStream_t s) {
  dim3 g((N + 63) / 64, M / 64);
  gemm_kernel<<<g, 256, 0, s>>>(X, W, bias, R, Y, M, N, K, wstride, relu);
}

extern "C" void kernel_launch(void* const* d_in, const int* in_sizes, int n_in,
                              void* d_out, int out_size, void* d_ws, size_t ws_size,
                              hipStream_t stream) {
  const float* memory   = (const float*)d_in[0];
  const float* person_q = (const float*)d_in[1];
  const float* key_q    = (const float*)d_in[2];
  const float* sa_in_w  = (const float*)d_in[3];
  const float* sa_in_b  = (const float*)d_in[4];
  const float* sa_out_w = (const float*)d_in[5];
  const float* sa_out_b = (const float*)d_in[6];
  const float* ca_in_w  = (const float*)d_in[7];
  const float* ca_in_b  = (const float*)d_in[8];
  const float* ca_out_w = (const float*)d_in[9];
  const float* ca_out_b = (const float*)d_in[10];
  const float* ff1_w = (const float*)d_in[11];
  const float* ff1_b = (const float*)d_in[12];
  const float* ff2_w = (const float*)d_in[13];
  const float* ff2_b = (const float*)d_in[14];
  const float* ln1_w = (const float*)d_in[15];
  const float* ln1_b = (const float*)d_in[16];
  const float* ln2_w = (const float*)d_in[17];
  const float* ln2_b = (const float*)d_in[18];
  const float* ln3_w = (const float*)d_in[19];
  const float* ln3_b = (const float*)d_in[20];
  const float* r1_w1 = (const float*)d_in[21];
  const float* r1_b1 = (const float*)d_in[22];
  const float* r1_w2 = (const float*)d_in[23];
  const float* r1_b2 = (const float*)d_in[24];
  const float* r2_w1 = (const float*)d_in[25];
  const float* r2_b1 = (const float*)d_in[26];
  const float* r2_w2 = (const float*)d_in[27];
  const float* r2_b2 = (const float*)d_in[28];
  const float* fc_w  = (const float*)d_in[29];
  const float* fc_b  = (const float*)d_in[30];
  float* out = (float*)d_out;

  // workspace layout (floats); total ~10.6M floats ~= 42.5 MB
  float* ws = (float*)d_ws;
  float* x      = ws; ws += (size_t)ROWS * DD;
  float* qkv    = ws; ws += (size_t)ROWS * 768;
  float* attn_o = ws; ws += (size_t)ROWS * DD;
  float* delta  = ws; ws += (size_t)ROWS * DD;
  float* q_ca   = ws; ws += (size_t)ROWS * DD;
  float* qk_eff = ws; ws += (size_t)ROWS * 2048;
  float* ctxb   = ws; ws += (size_t)ROWS * 2048;
  float* h_ff   = ws; ws += (size_t)ROWS * 2048;
  float* Wvo    = ws; ws += (size_t)3 * 256 * 2048;
  float* bvo    = ws; ws += 3 * 256;
  float* ubuf   = ws; ws += (size_t)ROWS * HIDD;
  float* vbuf   = ws; ws += (size_t)ROWS * HIDD;
  float* hbar   = ws; ws += (size_t)ROWS * HIDD;

  wvo_kernel<<<6144, 256, 0, stream>>>(ca_in_w, ca_out_w, Wvo);
  bvo_kernel<<<3, 256, 0, stream>>>(ca_out_w, ca_in_b, ca_out_b, bvo);
  init_x_kernel<<<ROWS, 256, 0, stream>>>(person_q, key_q, x);

  for (int l = 0; l < LL; ++l) {
    // --- self-attention ---
    gemm(x, sa_in_w + (size_t)l * 768 * 256, sa_in_b + l * 768, nullptr,
         qkv, ROWS, 768, 256, 256, 0, stream);
    sa_attn_kernel<<<512, 64, 0, stream>>>(qkv, attn_o);
    gemm(attn_o, sa_out_w + (size_t)l * 256 * 256, sa_out_b + l * 256, nullptr,
         delta, ROWS, 256, 256, 256, 0, stream);
    ln_kernel<<<ROWS, 256, 0, stream>>>(x, delta, ln1_w + l * 256, ln1_b + l * 256, x);
    // --- cross-attention (folded K/V projections) ---
    gemm(x, ca_in_w + (size_t)l * 768 * 256, ca_in_b + l * 768, nullptr,
         q_ca, ROWS, 256, 256, 256, 0, stream);
    qkeff_kernel<<<ROWS, 256, 0, stream>>>(q_ca, ca_in_w + (size_t)l * 768 * 256, qk_eff);
    ca_flash_kernel<<<512, 256, 0, stream>>>(qk_eff, memory, ctxb);
    gemm(ctxb, Wvo + (size_t)l * 256 * 2048, bvo + l * 256, nullptr,
         delta, ROWS, 256, 2048, 2048, 0, stream);
    ln_kernel<<<ROWS, 256, 0, stream>>>(x, delta, ln2_w + l * 256, ln2_b + l * 256, x);
    // --- feed-forward ---
    gemm(x, ff1_w + (size_t)l * 2048 * 256, ff1_b + l * 2048, nullptr,
         h_ff, ROWS, 2048, 256, 256, 1, stream);
    gemm(h_ff, ff2_w + (size_t)l * 256 * 2048, ff2_b + l * 256, nullptr,
         delta, ROWS, 256, 2048, 2048, 0, stream);
    ln_kernel<<<ROWS, 256, 0, stream>>>(x, delta, ln3_w + l * 256, ln3_b + l * 256, x);
  }

  // --- two refine blocks (pair MLP folded into u_i + v_j) ---
  const float* rw1[2] = {r1_w1, r2_w1};
  const float* rb1[2] = {r1_b1, r2_b1};
  const float* rw2[2] = {r1_w2, r2_w2};
  const float* rb2[2] = {r1_b2, r2_b2};
  for (int r = 0; r < 2; ++r) {
    gemm(x, rw1[r], rb1[r], nullptr, ubuf, ROWS, 128, 256, 512, 0, stream);
    gemm(x, rw1[r] + 256, nullptr, nullptr, vbuf, ROWS, 128, 256, 512, 0, stream);
    pairmean_kernel<<<64, 256, 0, stream>>>(ubuf, vbuf, hbar);
    gemm(hbar, rw2[r], rb2[r], x, x, ROWS, 256, 128, 128, 0, stream);
  }

  // --- final fc (N=3, guarded) ---
  gemm(x, fc_w, fc_b, nullptr, out, ROWS, 3, 256, 256, 0, stream);
}

// Round 2
// 1824.174 us; speedup vs baseline: 3.1267x; 3.1267x over previous
//
#include <hip/hip_runtime.h>
#include <stdint.h>

// Problem constants
#define NB   32
#define TSEQ 4096
#define DD   256
#define PP   2
#define KK   17
#define LL   3
#define NHH  8
#define HDD  32
#define FFD  2048
#define HIDD 128
#define ROWS 1088                    // B*P*K
#define SCALE 0.17677669529663689f   // 1/sqrt(32)

typedef __attribute__((ext_vector_type(4))) float f32x4;
typedef __attribute__((ext_vector_type(8))) short bf16x8;

// LDS strides (elements). 280 = 256+24, 88 = 64+24: chosen so row-coef mod 32
// banks is 12 -> all b128 fragment reads are 2-way (free) not 8-way.
#define MS 280
#define QS 280
#define PS 88

static __device__ __forceinline__ unsigned cvtpk(float lo, float hi) {
  unsigned r;
  asm volatile("v_cvt_pk_bf16_f32 %0, %1, %2" : "=v"(r) : "v"(lo), "v"(hi));
  return r;
}

// ---------- x init ----------
__global__ __launch_bounds__(256) void init_x_kernel(
    const float* __restrict__ person_q, const float* __restrict__ key_q,
    float* __restrict__ x) {
  const int row = blockIdx.x, tid = threadIdx.x;
  const int p = (row / KK) & 1, k = row % KK;
  x[(size_t)row * DD + tid] = person_q[p * DD + tid] + key_q[k * DD + tid];
}

// ---------- generic fp32 GEMM (unchanged) ----------
__global__ __launch_bounds__(256) void gemm_kernel(
    const float* __restrict__ X, const float* __restrict__ W,
    const float* __restrict__ bias, const float* __restrict__ R,
    float* __restrict__ Y, int M, int N, int K, int wstride, int relu) {
  __shared__ float As[16][68];
  __shared__ float Bs[16][68];
  const int tid = threadIdx.x;
  const int m0 = blockIdx.y * 64, n0 = blockIdx.x * 64;
  const int tr = tid >> 4, tc = tid & 15;
  const int lr = tid >> 2, lk = (tid & 3) << 2;
  float acc[4][4] = {{0.f, 0.f, 0.f, 0.f}, {0.f, 0.f, 0.f, 0.f},
                     {0.f, 0.f, 0.f, 0.f}, {0.f, 0.f, 0.f, 0.f}};
  for (int k0 = 0; k0 < K; k0 += 16) {
    const float4 av = *reinterpret_cast<const float4*>(&X[(size_t)(m0 + lr) * K + k0 + lk]);
    int wn = n0 + lr; if (wn >= N) wn = N - 1;
    const float4 bv = *reinterpret_cast<const float4*>(&W[(size_t)wn * wstride + k0 + lk]);
    __syncthreads();
    As[lk + 0][lr] = av.x; As[lk + 1][lr] = av.y; As[lk + 2][lr] = av.z; As[lk + 3][lr] = av.w;
    Bs[lk + 0][lr] = bv.x; Bs[lk + 1][lr] = bv.y; Bs[lk + 2][lr] = bv.z; Bs[lk + 3][lr] = bv.w;
    __syncthreads();
#pragma unroll
    for (int kk = 0; kk < 16; ++kk) {
      const float4 a = *reinterpret_cast<const float4*>(&As[kk][tr << 2]);
      const float4 b = *reinterpret_cast<const float4*>(&Bs[kk][tc << 2]);
      const float aa[4] = {a.x, a.y, a.z, a.w};
      const float bb[4] = {b.x, b.y, b.z, b.w};
#pragma unroll
      for (int r = 0; r < 4; ++r)
#pragma unroll
        for (int c = 0; c < 4; ++c) acc[r][c] += aa[r] * bb[c];
    }
  }
#pragma unroll
  for (int r = 0; r < 4; ++r) {
    const int m = m0 + (tr << 2) + r;
#pragma unroll
    for (int c = 0; c < 4; ++c) {
      const int n = n0 + (tc << 2) + c;
      if (n < N) {
        float o = acc[r][c];
        if (bias) o += bias[n];
        if (relu) o = fmaxf(o, 0.f);
        if (R) o += R[(size_t)m * N + n];
        Y[(size_t)m * N + n] = o;
      }
    }
  }
}

// ---------- self-attention over K=17 keypoints ----------
__global__ __launch_bounds__(64) void sa_attn_kernel(
    const float* __restrict__ qkv, float* __restrict__ attn_o) {
  const int blk = blockIdx.x;
  const int h = blk & 7, bp = blk >> 3;
  const int rowbase = bp * KK;
  const int tid = threadIdx.x;
  __shared__ float qs[KK][36], ks[KK][36], vs[KK][36];
  __shared__ float ss[KK][20];
  __shared__ float lsum[KK];
  for (int i = tid; i < KK * HDD; i += 64) {
    const int r = i >> 5, d = i & 31;
    const size_t base = (size_t)(rowbase + r) * 768 + h * 32 + d;
    qs[r][d] = qkv[base];
    ks[r][d] = qkv[base + 256];
    vs[r][d] = qkv[base + 512];
  }
  __syncthreads();
  for (int i = tid; i < KK * KK; i += 64) {
    const int q = i / KK, k = i % KK;
    float s = 0.f;
#pragma unroll
    for (int d = 0; d < HDD; ++d) s += qs[q][d] * ks[k][d];
    ss[q][k] = s * SCALE;
  }
  __syncthreads();
  if (tid < KK) {
    float m = -1e30f;
    for (int k = 0; k < KK; ++k) m = fmaxf(m, ss[tid][k]);
    float l = 0.f;
    for (int k = 0; k < KK; ++k) { const float e = __expf(ss[tid][k] - m); ss[tid][k] = e; l += e; }
    lsum[tid] = l;
  }
  __syncthreads();
  for (int i = tid; i < KK * HDD; i += 64) {
    const int q = i >> 5, d = i & 31;
    float o = 0.f;
#pragma unroll
    for (int k = 0; k < KK; ++k) o += ss[q][k] * vs[k][d];
    attn_o[(size_t)(rowbase + q) * DD + h * 32 + d] = o / lsum[q];
  }
}

// ---------- qk_eff[r,h,c] = scale * sum_j q[r, h*32+j] * Wk[h*32+j, c] ----------
__global__ __launch_bounds__(256) void qkeff_kernel(
    const float* __restrict__ q_ca, const float* __restrict__ ca_in_w_l,
    float* __restrict__ qk_eff) {
  const int r = blockIdx.x, tid = threadIdx.x;
  __shared__ float qrow[DD];
  qrow[tid] = q_ca[(size_t)r * DD + tid];
  __syncthreads();
#pragma unroll
  for (int h = 0; h < NHH; ++h) {
    float acc = 0.f;
#pragma unroll
    for (int j = 0; j < 32; ++j)
      acc += qrow[h * 32 + j] * ca_in_w_l[(size_t)(DD + h * 32 + j) * DD + tid];
    qk_eff[(size_t)r * 2048 + h * 256 + tid] = acc * SCALE;
  }
}

// ---------- fused MFMA cross-attention flash ----------
// grid 512 = b(32) x h(8) x T-half(2). block 256 = 4 waves.
// Per block: Q~ = 34 rows (pad 48) x 256, iterate 32 t-tiles of 64.
// Swapped QK^T: S^T = mem . Q^T  (A = mem rows, B = Q rows, both k-contiguous).
// Outputs unnormalized o + (m,l) per (row,h,half); combine kernel merges halves.
__global__ __launch_bounds__(256, 2) void ca_fused_kernel(
    const float* __restrict__ qk_eff, const float* __restrict__ memory,
    float* __restrict__ o_part, float* __restrict__ m_part, float* __restrict__ l_part) {
  const int half = blockIdx.x & 1;
  const int h = (blockIdx.x >> 1) & 7;
  const int b = blockIdx.x >> 4;
  const int tid = threadIdx.x;
  const int lane = tid & 63, w = tid >> 6;
  const int g = lane >> 4, q16 = lane & 15;

  __shared__ unsigned short mem_lds[64 * MS];
  __shared__ unsigned short q_lds[48 * QS];
  __shared__ unsigned short p_lds[48 * PS];
  __shared__ float red_m[48 * 4];
  __shared__ float red_l[48 * 4];
  __shared__ float r_lds[48];

  // --- stage Q (34 rows -> 48 padded) as bf16 ---
  for (int it = 0; it < 6; ++it) {
    const int idx = it * 256 + tid;          // < 1536 = 48*32
    const int q = idx >> 5, c8 = (idx & 31) << 3;
    uint4 st = {0u, 0u, 0u, 0u};
    if (q < 34) {
      const float* src = qk_eff + (size_t)(b * 34 + q) * 2048 + h * 256 + c8;
      const float4 f0 = *reinterpret_cast<const float4*>(src);
      const float4 f1 = *reinterpret_cast<const float4*>(src + 4);
      st.x = cvtpk(f0.x, f0.y); st.y = cvtpk(f0.z, f0.w);
      st.z = cvtpk(f1.x, f1.y); st.w = cvtpk(f1.z, f1.w);
    }
    *reinterpret_cast<uint4*>(&q_lds[q * QS + c8]) = st;
  }

  f32x4 ctx[3][4];
#pragma unroll
  for (int mt = 0; mt < 3; ++mt)
#pragma unroll
    for (int nt = 0; nt < 4; ++nt) ctx[mt][nt] = (f32x4){0.f, 0.f, 0.f, 0.f};
  float m_run[3] = {-1e30f, -1e30f, -1e30f};
  float l_run[3] = {0.f, 0.f, 0.f};

  const float* memb = memory + (size_t)b * TSEQ * DD;

  for (int tile = 0; tile < 32; ++tile) {
    const int tbase = half * 2048 + tile * 64;
    __syncthreads();   // guard mem_lds/p_lds/red reuse
    // --- stage mem tile 64x256 fp32 -> bf16 ---
    for (int it = 0; it < 8; ++it) {
      const int idx = it * 256 + tid;        // < 2048 = 64*32
      const int t = idx >> 5, c8 = (idx & 31) << 3;
      const float* src = memb + (size_t)(tbase + t) * DD + c8;
      const float4 f0 = *reinterpret_cast<const float4*>(src);
      const float4 f1 = *reinterpret_cast<const float4*>(src + 4);
      uint4 st;
      st.x = cvtpk(f0.x, f0.y); st.y = cvtpk(f0.z, f0.w);
      st.z = cvtpk(f1.x, f1.y); st.w = cvtpk(f1.z, f1.w);
      *reinterpret_cast<uint4*>(&mem_lds[t * MS + c8]) = st;
    }
    __syncthreads();

    // --- QK^T (swapped): S^T[t][q], wave w owns t-strip [w*16, w*16+16) ---
    f32x4 sacc[3];
#pragma unroll
    for (int qt = 0; qt < 3; ++qt) sacc[qt] = (f32x4){0.f, 0.f, 0.f, 0.f};
#pragma unroll
    for (int ks = 0; ks < 8; ++ks) {
      const bf16x8 af = *reinterpret_cast<const bf16x8*>(
          &mem_lds[(w * 16 + q16) * MS + ks * 32 + g * 8]);
#pragma unroll
      for (int qt = 0; qt < 3; ++qt) {
        const bf16x8 bq = *reinterpret_cast<const bf16x8*>(
            &q_lds[(qt * 16 + q16) * QS + ks * 32 + g * 8]);
        sacc[qt] = __builtin_amdgcn_mfma_f32_16x16x32_bf16(af, bq, sacc[qt], 0, 0, 0);
      }
    }
    // lane holds: col q = qt*16+q16, rows t = w*16 + g*4 + reg

    // --- per-q max over this wave's 16 t ---
#pragma unroll
    for (int qt = 0; qt < 3; ++qt) {
      float v = fmaxf(fmaxf(sacc[qt][0], sacc[qt][1]), fmaxf(sacc[qt][2], sacc[qt][3]));
      v = fmaxf(v, __shfl_xor(v, 16));
      v = fmaxf(v, __shfl_xor(v, 32));
      if (lane < 16) red_m[(qt * 16 + lane) * 4 + w] = v;
    }
    __syncthreads();

    float rfac[3], mnew[3];
#pragma unroll
    for (int qt = 0; qt < 3; ++qt) {
      const float4 rm = *reinterpret_cast<const float4*>(&red_m[(qt * 16 + q16) * 4]);
      const float tmax = fmaxf(fmaxf(rm.x, rm.y), fmaxf(rm.z, rm.w));
      mnew[qt] = fmaxf(m_run[qt], tmax);
      rfac[qt] = __expf(m_run[qt] - mnew[qt]);
      m_run[qt] = mnew[qt];
    }
    if (w == 0 && lane < 16) {
#pragma unroll
      for (int qt = 0; qt < 3; ++qt) r_lds[qt * 16 + lane] = rfac[qt];
    }

    // --- P = exp(S - m), write bf16 to p_lds[q][t], partial sums ---
#pragma unroll
    for (int qt = 0; qt < 3; ++qt) {
      const float p0 = __expf(sacc[qt][0] - mnew[qt]);
      const float p1 = __expf(sacc[qt][1] - mnew[qt]);
      const float p2 = __expf(sacc[qt][2] - mnew[qt]);
      const float p3 = __expf(sacc[qt][3] - mnew[qt]);
      const int prow = (qt * 16 + q16) * PS + w * 16 + g * 4;
      *reinterpret_cast<unsigned*>(&p_lds[prow]) = cvtpk(p0, p1);
      *reinterpret_cast<unsigned*>(&p_lds[prow + 2]) = cvtpk(p2, p3);
      float ps = (p0 + p1) + (p2 + p3);
      ps += __shfl_xor(ps, 16);
      ps += __shfl_xor(ps, 32);
      if (lane < 16) red_l[(qt * 16 + lane) * 4 + w] = ps;
    }
    __syncthreads();

#pragma unroll
    for (int qt = 0; qt < 3; ++qt) {
      const float4 rl = *reinterpret_cast<const float4*>(&red_l[(qt * 16 + q16) * 4]);
      l_run[qt] = l_run[qt] * rfac[qt] + ((rl.x + rl.y) + (rl.z + rl.w));
    }

    // --- rescale ctx ---
    float rr[3][4];
#pragma unroll
    for (int mt = 0; mt < 3; ++mt)
#pragma unroll
      for (int r = 0; r < 4; ++r) rr[mt][r] = r_lds[mt * 16 + g * 4 + r];
#pragma unroll
    for (int mt = 0; mt < 3; ++mt)
#pragma unroll
      for (int nt = 0; nt < 4; ++nt)
#pragma unroll
        for (int r = 0; r < 4; ++r) ctx[mt][nt][r] *= rr[mt][r];

    // --- PV: ctx[q][c] += P[q][t] . mem[t][c]; wave w owns c-slice w*64 ---
    bf16x8 pf[3][2];
#pragma unroll
    for (int mt = 0; mt < 3; ++mt)
#pragma unroll
      for (int ks = 0; ks < 2; ++ks)
        pf[mt][ks] = *reinterpret_cast<const bf16x8*>(
            &p_lds[(mt * 16 + q16) * PS + ks * 32 + g * 8]);
#pragma unroll
    for (int nt = 0; nt < 4; ++nt) {
#pragma unroll
      for (int ks = 0; ks < 2; ++ks) {
        const float* mp = memb + (size_t)(tbase + ks * 32 + g * 8) * DD
                          + w * 64 + nt * 16 + q16;
        union { bf16x8 v; unsigned u[4]; } bf;
        bf.u[0] = cvtpk(mp[0],       mp[DD]);
        bf.u[1] = cvtpk(mp[2 * DD],  mp[3 * DD]);
        bf.u[2] = cvtpk(mp[4 * DD],  mp[5 * DD]);
        bf.u[3] = cvtpk(mp[6 * DD],  mp[7 * DD]);
#pragma unroll
        for (int mt = 0; mt < 3; ++mt)
          ctx[mt][nt] = __builtin_amdgcn_mfma_f32_16x16x32_bf16(pf[mt][ks], bf.v,
                                                                ctx[mt][nt], 0, 0, 0);
      }
    }
  }

  // --- write unnormalized o + (m,l) ---
#pragma unroll
  for (int mt = 0; mt < 3; ++mt)
#pragma unroll
    for (int r = 0; r < 4; ++r) {
      const int q = mt * 16 + g * 4 + r;
      if (q < 34) {
        const size_t orow = (size_t)(half * ROWS + b * 34 + q) * 2048;
#pragma unroll
        for (int nt = 0; nt < 4; ++nt)
          o_part[orow + h * 256 + w * 64 + nt * 16 + q16] = ctx[mt][nt][r];
      }
    }
  if (w == 0 && lane < 16) {
#pragma unroll
    for (int qt = 0; qt < 3; ++qt) {
      const int q = qt * 16 + lane;
      if (q < 34) {
        const size_t idx = (size_t)(half * ROWS + b * 34 + q) * 8 + h;
        m_part[idx] = m_run[qt];
        l_part[idx] = l_run[qt];
      }
    }
  }
}

// ---------- combine the two T-halves ----------
__global__ __launch_bounds__(256) void ca_combine_kernel(
    const float* __restrict__ o_part, const float* __restrict__ m_part,
    const float* __restrict__ l_part, float* __restrict__ ctxb) {
  const int row = blockIdx.x, c = threadIdx.x;
#pragma unroll
  for (int h = 0; h < NHH; ++h) {
    const float m0 = m_part[(size_t)row * 8 + h];
    const float m1 = m_part[(size_t)(ROWS + row) * 8 + h];
    const float l0 = l_part[(size_t)row * 8 + h];
    const float l1 = l_part[(size_t)(ROWS + row) * 8 + h];
    const float M = fmaxf(m0, m1);
    const float w0 = __expf(m0 - M), w1 = __expf(m1 - M);
    const float denom = l0 * w0 + l1 * w1;
    const float o0 = o_part[(size_t)row * 2048 + h * 256 + c];
    const float o1 = o_part[(size_t)(ROWS + row) * 2048 + h * 256 + c];
    ctxb[(size_t)row * 2048 + h * 256 + c] = (o0 * w0 + o1 * w1) / denom;
  }
}

// ---------- residual + LayerNorm ----------
__global__ __launch_bounds__(256) void ln_kernel(
    const float* __restrict__ xin, const float* __restrict__ dlt,
    const float* __restrict__ w, const float* __restrict__ b,
    float* __restrict__ xout) {
  const int row = blockIdx.x, tid = threadIdx.x;
  const size_t base = (size_t)row * DD;
  const float v = xin[base + tid] + dlt[base + tid];
  float s = v, s2 = v * v;
#pragma unroll
  for (int off = 32; off > 0; off >>= 1) {
    s += __shfl_down(s, off);
    s2 += __shfl_down(s2, off);
  }
  __shared__ float ps[4], ps2[4];
  if ((tid & 63) == 0) { ps[tid >> 6] = s; ps2[tid >> 6] = s2; }
  __syncthreads();
  const float st = ps[0] + ps[1] + ps[2] + ps[3];
  const float st2 = ps2[0] + ps2[1] + ps2[2] + ps2[3];
  const float mean = st * (1.f / 256.f);
  const float var = st2 * (1.f / 256.f) - mean * mean;
  const float inv = rsqrtf(var + 1e-5f);
  xout[base + tid] = (v - mean) * inv * w[tid] + b[tid];
}

// ---------- W_vo / b_vo folding ----------
__global__ __launch_bounds__(256) void wvo_kernel(
    const float* __restrict__ ca_in_w, const float* __restrict__ ca_out_w,
    float* __restrict__ Wvo) {
  const int bx = blockIdx.x;
  const int h = bx & 7, dp = (bx >> 3) & 255, l = bx >> 11;
  const int c = threadIdx.x;
  const float* wout = ca_out_w + (size_t)l * 65536 + (size_t)dp * 256 + h * 32;
  const float* wv = ca_in_w + (size_t)l * 196608 + (size_t)(512 + h * 32) * 256 + c;
  float acc = 0.f;
#pragma unroll
  for (int j = 0; j < 32; ++j) acc += wout[j] * wv[(size_t)j * 256];
  Wvo[((size_t)l * 256 + dp) * 2048 + h * 256 + c] = acc;
}

__global__ __launch_bounds__(256) void bvo_kernel(
    const float* __restrict__ ca_out_w, const float* __restrict__ ca_in_b,
    const float* __restrict__ ca_out_b, float* __restrict__ bvo) {
  const int l = blockIdx.x, dp = threadIdx.x;
  float acc = ca_out_b[l * 256 + dp];
  for (int j = 0; j < 256; ++j)
    acc += ca_out_w[(size_t)l * 65536 + (size_t)dp * 256 + j] * ca_in_b[l * 768 + 512 + j];
  bvo[l * 256 + dp] = acc;
}

// ---------- refine pair-mean ----------
__global__ __launch_bounds__(256) void pairmean_kernel(
    const float* __restrict__ u, const float* __restrict__ v,
    float* __restrict__ hbar) {
  const int bp = blockIdx.x, tid = threadIdx.x;
  const int r0 = bp * KK;
  __shared__ float us[KK][132], vs[KK][132];
  for (int i = tid; i < KK * HIDD; i += 256) {
    const int r = i >> 7, f = i & 127;
    us[r][f] = u[(size_t)(r0 + r) * HIDD + f];
    vs[r][f] = v[(size_t)(r0 + r) * HIDD + f];
  }
  __syncthreads();
  for (int i = tid; i < KK * HIDD; i += 256) {
    const int r = i >> 7, f = i & 127;
    float s = 0.f;
#pragma unroll
    for (int j = 0; j < KK; ++j) s += fmaxf(us[r][f] + vs[j][f], 0.f);
    hbar[(size_t)(r0 + r) * HIDD + f] = s * (1.0f / 17.0f);
  }
}

static void gemm(const float* X, const float* W, const float* bias, const float* R,
                 float* Y, int M, int N, int K, int wstride, int relu, hipStream_t s) {
  dim3 g((N + 63) / 64, M / 64);
  gemm_kernel<<<g, 256, 0, s>>>(X, W, bias, R, Y, M, N, K, wstride, relu);
}

extern "C" void kernel_launch(void* const* d_in, const int* in_sizes, int n_in,
                              void* d_out, int out_size, void* d_ws, size_t ws_size,
                              hipStream_t stream) {
  const float* memory   = (const float*)d_in[0];
  const float* person_q = (const float*)d_in[1];
  const float* key_q    = (const float*)d_in[2];
  const float* sa_in_w  = (const float*)d_in[3];
  const float* sa_in_b  = (const float*)d_in[4];
  const float* sa_out_w = (const float*)d_in[5];
  const float* sa_out_b = (const float*)d_in[6];
  const float* ca_in_w  = (const float*)d_in[7];
  const float* ca_in_b  = (const float*)d_in[8];
  const float* ca_out_w = (const float*)d_in[9];
  const float* ca_out_b = (const float*)d_in[10];
  const float* ff1_w = (const float*)d_in[11];
  const float* ff1_b = (const float*)d_in[12];
  const float* ff2_w = (const float*)d_in[13];
  const float* ff2_b = (const float*)d_in[14];
  const float* ln1_w = (const float*)d_in[15];
  const float* ln1_b = (const float*)d_in[16];
  const float* ln2_w = (const float*)d_in[17];
  const float* ln2_b = (const float*)d_in[18];
  const float* ln3_w = (const float*)d_in[19];
  const float* ln3_b = (const float*)d_in[20];
  const float* r1_w1 = (const float*)d_in[21];
  const float* r1_b1 = (const float*)d_in[22];
  const float* r1_w2 = (const float*)d_in[23];
  const float* r1_b2 = (const float*)d_in[24];
  const float* r2_w1 = (const float*)d_in[25];
  const float* r2_b1 = (const float*)d_in[26];
  const float* r2_w2 = (const float*)d_in[27];
  const float* r2_b2 = (const float*)d_in[28];
  const float* fc_w  = (const float*)d_in[29];
  const float* fc_b  = (const float*)d_in[30];
  float* out = (float*)d_out;

  float* ws = (float*)d_ws;
  float* x      = ws; ws += (size_t)ROWS * DD;
  float* qkv    = ws; ws += (size_t)ROWS * 768;
  float* attn_o = ws; ws += (size_t)ROWS * DD;
  float* delta  = ws; ws += (size_t)ROWS * DD;
  float* q_ca   = ws; ws += (size_t)ROWS * DD;
  float* qk_eff = ws; ws += (size_t)ROWS * 2048;
  float* ctxb   = ws; ws += (size_t)ROWS * 2048;
  float* h_ff   = ws; ws += (size_t)ROWS * 2048;
  float* Wvo    = ws; ws += (size_t)3 * 256 * 2048;
  float* bvo    = ws; ws += 3 * 256;
  float* ubuf   = ws; ws += (size_t)ROWS * HIDD;
  float* vbuf   = ws; ws += (size_t)ROWS * HIDD;
  float* hbar   = ws; ws += (size_t)ROWS * HIDD;
  float* o_part = ws; ws += (size_t)2 * ROWS * 2048;   // 17.8 MB
  float* m_part = ws; ws += (size_t)2 * ROWS * 8;
  float* l_part = ws; ws += (size_t)2 * ROWS * 8;

  wvo_kernel<<<6144, 256, 0, stream>>>(ca_in_w, ca_out_w, Wvo);
  bvo_kernel<<<3, 256, 0, stream>>>(ca_out_w, ca_in_b, ca_out_b, bvo);
  init_x_kernel<<<ROWS, 256, 0, stream>>>(person_q, key_q, x);

  for (int l = 0; l < LL; ++l) {
    // --- self-attention ---
    gemm(x, sa_in_w + (size_t)l * 768 * 256, sa_in_b + l * 768, nullptr,
         qkv, ROWS, 768, 256, 256, 0, stream);
    sa_attn_kernel<<<512, 64, 0, stream>>>(qkv, attn_o);
    gemm(attn_o, sa_out_w + (size_t)l * 256 * 256, sa_out_b + l * 256, nullptr,
         delta, ROWS, 256, 256, 256, 0, stream);
    ln_kernel<<<ROWS, 256, 0, stream>>>(x, delta, ln1_w + l * 256, ln1_b + l * 256, x);
    // --- cross-attention (folded K/V projections, MFMA flash) ---
    gemm(x, ca_in_w + (size_t)l * 768 * 256, ca_in_b + l * 768, nullptr,
         q_ca, ROWS, 256, 256, 256, 0, stream);
    qkeff_kernel<<<ROWS, 256, 0, stream>>>(q_ca, ca_in_w + (size_t)l * 768 * 256, qk_eff);
    ca_fused_kernel<<<512, 256, 0, stream>>>(qk_eff, memory, o_part, m_part, l_part);
    ca_combine_kernel<<<ROWS, 256, 0, stream>>>(o_part, m_part, l_part, ctxb);
    gemm(ctxb, Wvo + (size_t)l * 256 * 2048, bvo + l * 256, nullptr,
         delta, ROWS, 256, 2048, 2048, 0, stream);
    ln_kernel<<<ROWS, 256, 0, stream>>>(x, delta, ln2_w + l * 256, ln2_b + l * 256, x);
    // --- feed-forward ---
    gemm(x, ff1_w + (size_t)l * 2048 * 256, ff1_b + l * 2048, nullptr,
         h_ff, ROWS, 2048, 256, 256, 1, stream);
    gemm(h_ff, ff2_w + (size_t)l * 256 * 2048, ff2_b + l * 256, nullptr,
         delta, ROWS, 256, 2048, 2048, 0, stream);
    ln_kernel<<<ROWS, 256, 0, stream>>>(x, delta, ln3_w + l * 256, ln3_b + l * 256, x);
  }

  const float* rw1[2] = {r1_w1, r2_w1};
  const float* rb1[2] = {r1_b1, r2_b1};
  const float* rw2[2] = {r1_w2, r2_w2};
  const float* rb2[2] = {r1_b2, r2_b2};
  for (int r = 0; r < 2; ++r) {
    gemm(x, rw1[r], rb1[r], nullptr, ubuf, ROWS, 128, 256, 512, 0, stream);
    gemm(x, rw1[r] + 256, nullptr, nullptr, vbuf, ROWS, 128, 256, 512, 0, stream);
    pairmean_kernel<<<64, 256, 0, stream>>>(ubuf, vbuf, hbar);
    gemm(hbar, rw2[r], rb2[r], x, x, ROWS, 256, 128, 128, 0, stream);
  }

  gemm(x, fc_w, fc_b, nullptr, out, ROWS, 3, 256, 256, 0, stream);
}